// Round 9
// baseline (178.334 us; speedup 1.0000x reference)
//
#include <hip/hip_runtime.h>
#include <hip/hip_bf16.h>

// B=4, T=2048, C=1024, H=16, D=64
//
// ws (ushort elems), 67.1MB:
//   ws0 [0..8388608)         q [B,H,T,D] (pre-scaled by 0.125*log2e) -> WoutT
//   ws1 [8388608..16777216)  k [B,H,T,D]
//   ws2 [16777216..25165824) vT [B,H,D,T] (written directly by gemm1 epilogue)
//   ws3 [25165824..33554432) y [B*T,C]
// d_out scratch early (dead before final GEMM): xbf [8192][1024], WqkvT [3072][1024]

using f32x4 = __attribute__((ext_vector_type(4))) float;
using s16x8 = __attribute__((ext_vector_type(8))) short;
using s16x4 = __attribute__((ext_vector_type(4))) short;

#define MFMA16(a, b, c) __builtin_amdgcn_mfma_f32_16x16x32_bf16(a, b, c, 0, 0, 0)

__device__ __forceinline__ unsigned short f2bf(float f) {
    unsigned u = __builtin_bit_cast(unsigned, f);
    u += 0x7fffu + ((u >> 16) & 1u);
    return (unsigned short)(u >> 16);
}

__device__ __forceinline__ void gl_lds16(const void* g, void* l) {
    __builtin_amdgcn_global_load_lds(
        (const __attribute__((address_space(1))) void*)g,
        (__attribute__((address_space(3))) void*)l, 16, 0, 0);
}

// ---------------------------------------------------------------------------
__global__ __launch_bounds__(256) void cvt_x(const float* __restrict__ x,
                                             unsigned short* __restrict__ xb, int n4) {
    int i = blockIdx.x * 256 + threadIdx.x;
    if (i < n4) {
        f32x4 v = ((const f32x4*)x)[i];
        s16x4 o;
        o[0] = (short)f2bf(v[0]); o[1] = (short)f2bf(v[1]);
        o[2] = (short)f2bf(v[2]); o[3] = (short)f2bf(v[3]);
        ((s16x4*)xb)[i] = o;
    }
}

// ---------------------------------------------------------------------------
__global__ __launch_bounds__(256) void cvt_tr(const float* __restrict__ W,
                                              unsigned short* __restrict__ Wt,
                                              int R, int Cc) {
    __shared__ unsigned short tile[64][72];
    const int r0 = blockIdx.x * 64, c0 = blockIdx.y * 64;
    const int tid = threadIdx.x;
    const int r = tid >> 4, c4 = (tid & 15) * 4;
#pragma unroll
    for (int i = 0; i < 4; ++i) {
        f32x4 v = *(const f32x4*)(W + (size_t)(r0 + r + i * 16) * Cc + c0 + c4);
#pragma unroll
        for (int j = 0; j < 4; ++j) tile[r + i * 16][c4 + j] = f2bf(v[j]);
    }
    __syncthreads();
#pragma unroll
    for (int i = 0; i < 4; ++i) {
        s16x4 o;
#pragma unroll
        for (int j = 0; j < 4; ++j) o[j] = (short)tile[c4 + j][r + i * 16];
        *(s16x4*)(Wt + (size_t)(c0 + r + i * 16) * R + r0 + c4) = o;
    }
}

// ---------------------------------------------------------------------------
// GEMM, T3-minimum pipelined structure (verified round 8):
//   128x128 tile, BK=64, 4 waves (2x2), double-buffered LDS (2x32KB),
//   stage(t+1) issued BEFORE compute(t), one vmcnt(0)+barrier per K-step,
//   XOR-swizzled LDS, setprio around the 32-MFMA cluster.
// MODE 0: scatter q/k row-layout (q pre-scaled) + v transposed to vT.
// MODE 1: fp32 out [M][N].
// ---------------------------------------------------------------------------
template <int MODE>
__global__ __launch_bounds__(256, 2) void gemm_bt(
    const unsigned short* __restrict__ A, const unsigned short* __restrict__ Bt,
    const float* __restrict__ bias,
    unsigned short* __restrict__ qp, unsigned short* __restrict__ kp,
    unsigned short* __restrict__ vtp, float* __restrict__ outp,
    int M, int N, int K)
{
    __shared__ unsigned short As[2][128 * 64];
    __shared__ unsigned short Bs[2][128 * 64];

    const int tid  = threadIdx.x;
    const int lane = tid & 63, w = tid >> 6;
    const int wm = w >> 1, wn = w & 1;
    const int g = lane >> 4, li = lane & 15;
    const int m0 = blockIdx.x * 128, n0 = blockIdx.y * 128;

    const int srow = lane >> 3;                    // 0..7 within an 8-row issue
    const int ssw  = ((lane & 7) ^ srow) * 8;      // pre-swizzled source chunk

    f32x4 acc[4][4] = {};

    auto STAGE = [&](int buf, int k0) {
#pragma unroll
        for (int j = 0; j < 4; ++j) {
            const int rr = w * 32 + j * 8;         // wave-uniform base row
            gl_lds16(A  + (size_t)(m0 + rr + srow) * K + k0 + ssw, &As[buf][rr * 64]);
            gl_lds16(Bt + (size_t)(n0 + rr + srow) * K + k0 + ssw, &Bs[buf][rr * 64]);
        }
    };

    STAGE(0, 0);
    asm volatile("s_waitcnt vmcnt(0)" ::: "memory");
    __syncthreads();

    const int nt = K >> 6;
    int cur = 0;
    for (int t = 0; t < nt; ++t) {
        if (t + 1 < nt) STAGE(cur ^ 1, (t + 1) << 6);   // issue-early prefetch

        s16x8 af[4][2], bf[4][2];
#pragma unroll
        for (int i = 0; i < 4; ++i) {
            const int ra = wm * 64 + i * 16 + li;
            const int rb = wn * 64 + i * 16 + li;
#pragma unroll
            for (int kk = 0; kk < 2; ++kk) {
                af[i][kk] = *(const s16x8*)(
                    &As[cur][ra * 64 + (((kk * 4 + g) ^ (ra & 7)) << 3)]);
                bf[i][kk] = *(const s16x8*)(
                    &Bs[cur][rb * 64 + (((kk * 4 + g) ^ (rb & 7)) << 3)]);
            }
        }

        __builtin_amdgcn_s_setprio(1);
#pragma unroll
        for (int kk = 0; kk < 2; ++kk)
#pragma unroll
            for (int mi = 0; mi < 4; ++mi)
#pragma unroll
                for (int ni = 0; ni < 4; ++ni)
                    acc[mi][ni] = MFMA16(af[mi][kk], bf[ni][kk], acc[mi][ni]);
        __builtin_amdgcn_s_setprio(0);

        asm volatile("s_waitcnt vmcnt(0)" ::: "memory");
        __syncthreads();
        cur ^= 1;
    }

#pragma unroll
    for (int ni = 0; ni < 4; ++ni) {
        const int n = n0 + wn * 64 + ni * 16 + li;
        const float bv = bias[n];
        const int s = n >> 10, h = (n >> 6) & 15, d = n & 63;
#pragma unroll
        for (int mi = 0; mi < 4; ++mi) {
            const int mB = m0 + wm * 64 + mi * 16 + g * 4;
            float v0 = acc[mi][ni][0] + bv, v1 = acc[mi][ni][1] + bv;
            float v2 = acc[mi][ni][2] + bv, v3 = acc[mi][ni][3] + bv;
            if (MODE == 0) {
                const int b = mB >> 11, tt = mB & 2047;
                if (s == 2) {
                    unsigned pk01, pk23;
                    asm("v_cvt_pk_bf16_f32 %0, %1, %2" : "=v"(pk01) : "v"(v0), "v"(v1));
                    asm("v_cvt_pk_bf16_f32 %0, %1, %2" : "=v"(pk23) : "v"(v2), "v"(v3));
                    unsigned short* dst = vtp + ((size_t)(b * 16 + h) * 64 + d) * 2048 + tt;
                    *(unsigned*)dst = pk01;
                    *(unsigned*)(dst + 2) = pk23;
                } else {
                    const float sc2 = (s == 0) ? 0.1803368801111143f : 1.0f;  // 0.125*log2e
                    unsigned short* dst =
                        ((s == 0) ? qp : kp) + ((size_t)(b * 16 + h) * 2048 + tt) * 64 + d;
                    dst[0]   = f2bf(v0 * sc2);
                    dst[64]  = f2bf(v1 * sc2);
                    dst[128] = f2bf(v2 * sc2);
                    dst[192] = f2bf(v3 * sc2);
                }
            } else {
                float* dst = outp + (size_t)mB * N + n;
                dst[0] = v0; dst[N] = v1; dst[2 * N] = v2; dst[3 * N] = v3;
            }
        }
    }
}

// ---------------------------------------------------------------------------
// Flash attention, causal.
//   - 4 waves/block; block owns q-tile pair (A = 31-bx heavy, B = bx light);
//     single kv-loop, K/V staged once per t, shared by both tiles + 4 waves.
//   - T14 async-STAGE: global loads for t+1 issued into REGISTERS at the top
//     of iter t (latency hides under compute); ds_write after the barrier.
//     Single K/V LDS buffer, single shared Ps buffer (LDS 25.6KB).
//   - XCD swizzle; swapped QK^T; defer-max; setprio; exp2 domain.
// ---------------------------------------------------------------------------
__device__ __forceinline__ void stage_load(
    const unsigned short* __restrict__ kb, const unsigned short* __restrict__ vtb,
    int kbase, int w, int lane, s16x8 (&kr)[2], s16x8 (&vr)[2])
{
    const int srow = lane >> 3;
    const int sw = ((lane & 7) ^ srow) * 8;   // pre-swizzled source chunk
#pragma unroll
    for (int jj = 0; jj < 2; ++jj) {
        const int row = (w * 2 + jj) * 8 + srow;  // local row (key for K, d for vT)
        kr[jj] = *(const s16x8*)(kb + (size_t)(kbase + row) * 64 + sw);
        vr[jj] = *(const s16x8*)(vtb + (size_t)row * 2048 + kbase + sw);
    }
}

__device__ __forceinline__ void stage_write(
    unsigned short* Ks, unsigned short* Vs, int w, int lane,
    const s16x8 (&kr)[2], const s16x8 (&vr)[2])
{
#pragma unroll
    for (int jj = 0; jj < 2; ++jj) {
        const int j = w * 2 + jj;
        *(s16x8*)(Ks + j * 512 + lane * 8) = kr[jj];   // same layout as gl_lds16
        *(s16x8*)(Vs + j * 512 + lane * 8) = vr[jj];
    }
}

// QK^T + online softmax + P staging for one q-tile; returns P fragments.
__device__ __forceinline__ void qk_softmax(
    const unsigned short* Ks, const s16x8 qf0, const s16x8 qf1,
    f32x4 (&O)[4], float& m, float& l,
    unsigned short (*Psw)[72], s16x8& pf0, s16x8& pf1,
    int kbase, int wq0, int qrow, int g, int li)
{
    f32x4 sT[4];
    __builtin_amdgcn_s_setprio(1);
#pragma unroll
    for (int nf = 0; nf < 4; ++nf) {
        const int r = nf * 16 + li;
        s16x8 kf0 = *(const s16x8*)(Ks + r * 64 + ((g ^ (li & 7)) << 3));
        s16x8 kf1 = *(const s16x8*)(Ks + r * 64 + (((g + 4) ^ (li & 7)) << 3));
        f32x4 a = {};
        a = MFMA16(kf0, qf0, a);
        a = MFMA16(kf1, qf1, a);
        sT[nf] = a;
    }
    __builtin_amdgcn_s_setprio(0);

    if (kbase + 63 > wq0) {
#pragma unroll
        for (int nf = 0; nf < 4; ++nf)
#pragma unroll
            for (int r = 0; r < 4; ++r)
                if (kbase + nf * 16 + g * 4 + r > qrow) sT[nf][r] = -1e30f;
    }

    float t0 = fmaxf(fmaxf(sT[0][0], sT[0][1]), sT[0][2]);
    float t1 = fmaxf(fmaxf(sT[0][3], sT[1][0]), sT[1][1]);
    float t2 = fmaxf(fmaxf(sT[1][2], sT[1][3]), sT[2][0]);
    float t3 = fmaxf(fmaxf(sT[2][1], sT[2][2]), sT[2][3]);
    float t4 = fmaxf(fmaxf(sT[3][0], sT[3][1]), sT[3][2]);
    float mx = fmaxf(fmaxf(t0, t1), t2);
    mx = fmaxf(fmaxf(mx, t3), fmaxf(t4, sT[3][3]));
    mx = fmaxf(mx, __shfl_xor(mx, 16));
    mx = fmaxf(mx, __shfl_xor(mx, 32));

    if (__any(mx > m + 8.f)) {
        const float mnew = fmaxf(m, mx);
        const float fac  = __builtin_amdgcn_exp2f(m - mnew);
        m = mnew;
        l *= fac;
        float facr[4];
#pragma unroll
        for (int r = 0; r < 4; ++r) facr[r] = __shfl(fac, g * 4 + r);
#pragma unroll
        for (int nf = 0; nf < 4; ++nf)
#pragma unroll
            for (int r = 0; r < 4; ++r) O[nf][r] *= facr[r];
    }

    float rs = 0.f;
#pragma unroll
    for (int nf = 0; nf < 4; ++nf)
#pragma unroll
        for (int r = 0; r < 4; ++r) {
            float p = __builtin_amdgcn_exp2f(sT[nf][r] - m);
            sT[nf][r] = p;
            rs += p;
        }
    rs += __shfl_xor(rs, 16);
    rs += __shfl_xor(rs, 32);
    l += rs;

#pragma unroll
    for (int nf = 0; nf < 4; ++nf) {
        unsigned pk0, pk1;
        asm("v_cvt_pk_bf16_f32 %0, %1, %2" : "=v"(pk0) : "v"(sT[nf][0]), "v"(sT[nf][1]));
        asm("v_cvt_pk_bf16_f32 %0, %1, %2" : "=v"(pk1) : "v"(sT[nf][2]), "v"(sT[nf][3]));
        uint2 pv; pv.x = pk0; pv.y = pk1;
        *(uint2*)(&Psw[li][nf * 16 + g * 4]) = pv;
    }
    pf0 = *(const s16x8*)(&Psw[li][g * 8]);
    pf1 = *(const s16x8*)(&Psw[li][32 + g * 8]);
}

__global__ __launch_bounds__(256, 4) void attn_k(
    const unsigned short* __restrict__ qbuf,
    const unsigned short* __restrict__ kbuf,
    const unsigned short* __restrict__ vtbuf,
    unsigned short* __restrict__ ybuf)
{
    __shared__ unsigned short Ks[4096];       // [64 keys][64 d], swizzled
    __shared__ unsigned short Vs[4096];       // [64 d][64 keys], swizzled
    __shared__ unsigned short Ps[4][16][72];  // per-wave P staging (shared A/B)

    const int tid  = threadIdx.x;
    const int lane = tid & 63, w = tid >> 6;
    const int g = lane >> 4, li = lane & 15;

    // XCD-aware remap: XCD x (= id%8) owns bh in [8x, 8x+8) -> K/V fits L2
    const int id   = blockIdx.x;
    const int slot = id >> 3;
    const int bh   = (id & 7) * 8 + (slot & 7);
    const int bx   = slot >> 3;               // 0..15
    const int qtA  = 31 - bx, qtB = bx;

    const unsigned short* qb  = qbuf  + (size_t)bh * 131072;
    const unsigned short* kb  = kbuf  + (size_t)bh * 131072;
    const unsigned short* vtb = vtbuf + (size_t)bh * 131072;
    const int b = bh >> 4, h = bh & 15;

    const int wqA = qtA * 64 + w * 16, qrowA = wqA + li;
    const int wqB = qtB * 64 + w * 16, qrowB = wqB + li;

    const unsigned short* qrA = qb + (size_t)qrowA * 64 + g * 8;
    const s16x8 qfA0 = *(const s16x8*)qrA;
    const s16x8 qfA1 = *(const s16x8*)(qrA + 32);
    const unsigned short* qrB = qb + (size_t)qrowB * 64 + g * 8;
    const s16x8 qfB0 = *(const s16x8*)qrB;
    const s16x8 qfB1 = *(const s16x8*)(qrB + 32);

    f32x4 OA[4] = {}, OB[4] = {};
    float mA = -1e30f, lA = 0.f, mB = -1e30f, lB = 0.f;

    const int nkb = qtA + 1;
    s16x8 kr[2], vr[2];
    stage_load(kb, vtb, 0, w, lane, kr, vr);
    stage_write(Ks, Vs, w, lane, kr, vr);     // compiler waits vmcnt for deps
    __syncthreads();

    for (int t = 0; t < nkb; ++t) {
        const int kbase = t * 64;
        const bool actB = (t <= qtB);
        const bool more = (t + 1 < nkb);

        if (more) stage_load(kb, vtb, kbase + 64, w, lane, kr, vr);  // issue early

        s16x8 pfA0, pfA1, pfB0, pfB1;
        qk_softmax(Ks, qfA0, qfA1, OA, mA, lA, &Ps[w][0], pfA0, pfA1,
                   kbase, wqA, qrowA, g, li);
        if (actB)
            qk_softmax(Ks, qfB0, qfB1, OB, mB, lB, &Ps[w][0], pfB0, pfB1,
                       kbase, wqB, qrowB, g, li);

        // PV: shared V fragments feed both tiles
        __builtin_amdgcn_s_setprio(1);
#pragma unroll
        for (int nf = 0; nf < 4; ++nf) {
            const int d = nf * 16 + li;
            s16x8 vf0 = *(const s16x8*)(Vs + d * 64 + ((g ^ (li & 7)) << 3));
            s16x8 vf1 = *(const s16x8*)(Vs + d * 64 + (((g + 4) ^ (li & 7)) << 3));
            OA[nf] = MFMA16(pfA0, vf0, OA[nf]);
            OA[nf] = MFMA16(pfA1, vf1, OA[nf]);
            if (actB) {
                OB[nf] = MFMA16(pfB0, vf0, OB[nf]);
                OB[nf] = MFMA16(pfB1, vf1, OB[nf]);
            }
        }
        __builtin_amdgcn_s_setprio(0);

        if (more) {
            __syncthreads();                  // all waves done reading Ks/Vs
            stage_write(Ks, Vs, w, lane, kr, vr);  // regs ready (vmcnt dep)
            __syncthreads();                  // writes visible
        }
    }

    // epilogue: per-tile linv broadcast to D-layout rows, write y
    {
        const float linv = __builtin_amdgcn_rcpf(lA);
        float lr[4];
#pragma unroll
        for (int r = 0; r < 4; ++r) lr[r] = __shfl(linv, g * 4 + r);
#pragma unroll
        for (int nf = 0; nf < 4; ++nf)
#pragma unroll
            for (int r = 0; r < 4; ++r) {
                const int row = wqA + g * 4 + r;
                ybuf[((size_t)(b * 2048 + row)) * 1024 + h * 64 + nf * 16 + li] =
                    f2bf(OA[nf][r] * lr[r]);
            }
    }
    {
        const float linv = __builtin_amdgcn_rcpf(lB);
        float lr[4];
#pragma unroll
        for (int r = 0; r < 4; ++r) lr[r] = __shfl(linv, g * 4 + r);
#pragma unroll
        for (int nf = 0; nf < 4; ++nf)
#pragma unroll
            for (int r = 0; r < 4; ++r) {
                const int row = wqB + g * 4 + r;
                ybuf[((size_t)(b * 2048 + row)) * 1024 + h * 64 + nf * 16 + li] =
                    f2bf(OB[nf][r] * lr[r]);
            }
    }
}

extern "C" void kernel_launch(void* const* d_in, const int* in_sizes, int n_in,
                              void* d_out, int out_size, void* d_ws, size_t ws_size,
                              hipStream_t stream)
{
    const float* x    = (const float*)d_in[0];
    const float* Wqkv = (const float*)d_in[1];
    const float* bqkv = (const float*)d_in[2];
    const float* Wout = (const float*)d_in[3];
    const float* bout = (const float*)d_in[4];

    unsigned short* ws0 = (unsigned short*)d_ws;               // q -> WoutT
    unsigned short* ws1 = ws0 + (size_t)8388608;               // k
    unsigned short* ws2 = ws0 + (size_t)2 * 8388608;           // vT
    unsigned short* ws3 = ws0 + (size_t)3 * 8388608;           // y

    unsigned short* xbf   = (unsigned short*)d_out;
    unsigned short* WqkvT = xbf + (size_t)8388608;

    cvt_x<<<8192, 256, 0, stream>>>(x, xbf, 2097152);
    cvt_tr<<<dim3(16, 48), 256, 0, stream>>>(Wqkv, WqkvT, 1024, 3072);
    gemm_bt<0><<<dim3(64, 24), 256, 0, stream>>>(
        xbf, WqkvT, bqkv, ws0, ws1, ws2, nullptr, 8192, 3072, 1024);
    attn_k<<<1024, 256, 0, stream>>>(ws0, ws1, ws2, ws3);
    cvt_tr<<<dim3(16, 16), 256, 0, stream>>>(Wout, ws0, 1024, 1024);
    gemm_bt<1><<<dim3(64, 8), 256, 0, stream>>>(
        ws3, ws0, bout, nullptr, nullptr, nullptr, (float*)d_out, 8192, 1024, 1024);
}

// Round 10
// 165.157 us; speedup vs baseline: 1.0798x; 1.0798x over previous
//
#include <hip/hip_runtime.h>
#include <hip/hip_bf16.h>

// B=4, T=2048, C=1024, H=16, D=64
//
// ws (ushort elems), 67.1MB:
//   ws0 [0..8388608)         q [B,H,T,D] (pre-scaled by 0.125*log2e) -> WoutT
//   ws1 [8388608..16777216)  k [B,H,T,D]
//   ws2 [16777216..25165824) vT [B,H,D,T] (written directly by gemm1 epilogue)
//   ws3 [25165824..33554432) y [B*T,C]
// d_out scratch early (dead before final GEMM): xbf [8192][1024], WqkvT [3072][1024]

using f32x4 = __attribute__((ext_vector_type(4))) float;
using s16x8 = __attribute__((ext_vector_type(8))) short;
using s16x4 = __attribute__((ext_vector_type(4))) short;

#define MFMA16(a, b, c) __builtin_amdgcn_mfma_f32_16x16x32_bf16(a, b, c, 0, 0, 0)

__device__ __forceinline__ unsigned short f2bf(float f) {
    unsigned u = __builtin_bit_cast(unsigned, f);
    u += 0x7fffu + ((u >> 16) & 1u);
    return (unsigned short)(u >> 16);
}

__device__ __forceinline__ void gl_lds16(const void* g, void* l) {
    __builtin_amdgcn_global_load_lds(
        (const __attribute__((address_space(1))) void*)g,
        (__attribute__((address_space(3))) void*)l, 16, 0, 0);
}

#define VMCNT(N) asm volatile("s_waitcnt vmcnt(" #N ")" ::: "memory")
#define RBAR()   __builtin_amdgcn_s_barrier()

// ---------------------------------------------------------------------------
__global__ __launch_bounds__(256) void cvt_x(const float* __restrict__ x,
                                             unsigned short* __restrict__ xb, int n4) {
    int i = blockIdx.x * 256 + threadIdx.x;
    if (i < n4) {
        f32x4 v = ((const f32x4*)x)[i];
        s16x4 o;
        o[0] = (short)f2bf(v[0]); o[1] = (short)f2bf(v[1]);
        o[2] = (short)f2bf(v[2]); o[3] = (short)f2bf(v[3]);
        ((s16x4*)xb)[i] = o;
    }
}

// ---------------------------------------------------------------------------
__global__ __launch_bounds__(256) void cvt_tr(const float* __restrict__ W,
                                              unsigned short* __restrict__ Wt,
                                              int R, int Cc) {
    __shared__ unsigned short tile[64][72];
    const int r0 = blockIdx.x * 64, c0 = blockIdx.y * 64;
    const int tid = threadIdx.x;
    const int r = tid >> 4, c4 = (tid & 15) * 4;
#pragma unroll
    for (int i = 0; i < 4; ++i) {
        f32x4 v = *(const f32x4*)(W + (size_t)(r0 + r + i * 16) * Cc + c0 + c4);
#pragma unroll
        for (int j = 0; j < 4; ++j) tile[r + i * 16][c4 + j] = f2bf(v[j]);
    }
    __syncthreads();
#pragma unroll
    for (int i = 0; i < 4; ++i) {
        s16x4 o;
#pragma unroll
        for (int j = 0; j < 4; ++j) o[j] = (short)tile[c4 + j][r + i * 16];
        *(s16x4*)(Wt + (size_t)(c0 + r + i * 16) * R + r0 + c4) = o;
    }
}

// ---------------------------------------------------------------------------
// GEMM: 128x128 tile, BK=64, 4 waves (2x2), double-buffered LDS,
// counted-vmcnt pipeline: STAGE(t+1) issued at top, wait vmcnt(8) (old tile
// only), raw barriers — prefetch stays in flight across barriers (T4).
// MODE 0: scatter q/k row-layout (q pre-scaled) + v transposed to vT.
// MODE 1: fp32 out [M][N].
// ---------------------------------------------------------------------------
template <int MODE>
__global__ __launch_bounds__(256, 2) void gemm_bt(
    const unsigned short* __restrict__ A, const unsigned short* __restrict__ Bt,
    const float* __restrict__ bias,
    unsigned short* __restrict__ qp, unsigned short* __restrict__ kp,
    unsigned short* __restrict__ vtp, float* __restrict__ outp,
    int M, int N, int K)
{
    __shared__ unsigned short As[2][128 * 64];
    __shared__ unsigned short Bs[2][128 * 64];

    const int tid  = threadIdx.x;
    const int lane = tid & 63, w = tid >> 6;
    const int wm = w >> 1, wn = w & 1;
    const int g = lane >> 4, li = lane & 15;
    const int m0 = blockIdx.x * 128, n0 = blockIdx.y * 128;

    const int srow = lane >> 3;                    // 0..7 within an 8-row issue
    const int ssw  = ((lane & 7) ^ srow) * 8;      // pre-swizzled source chunk

    f32x4 acc[4][4] = {};

    auto STAGE = [&](int buf, int k0) {
#pragma unroll
        for (int j = 0; j < 4; ++j) {
            const int rr = w * 32 + j * 8;         // wave-uniform base row
            gl_lds16(A  + (size_t)(m0 + rr + srow) * K + k0 + ssw, &As[buf][rr * 64]);
            gl_lds16(Bt + (size_t)(n0 + rr + srow) * K + k0 + ssw, &Bs[buf][rr * 64]);
        }
    };

    STAGE(0, 0);

    const int nt = K >> 6;
    int cur = 0;
    for (int t = 0; t < nt; ++t) {
        if (t + 1 < nt) {
            STAGE(cur ^ 1, (t + 1) << 6);          // issue next (8 loads)
            VMCNT(8);                              // wait current tile only
        } else {
            VMCNT(0);
        }
        RBAR();                                    // current tile visible

        s16x8 af[4][2], bf[4][2];
#pragma unroll
        for (int i = 0; i < 4; ++i) {
            const int ra = wm * 64 + i * 16 + li;
            const int rb = wn * 64 + i * 16 + li;
#pragma unroll
            for (int kk = 0; kk < 2; ++kk) {
                af[i][kk] = *(const s16x8*)(
                    &As[cur][ra * 64 + (((kk * 4 + g) ^ (ra & 7)) << 3)]);
                bf[i][kk] = *(const s16x8*)(
                    &Bs[cur][rb * 64 + (((kk * 4 + g) ^ (rb & 7)) << 3)]);
            }
        }

        __builtin_amdgcn_s_setprio(1);
#pragma unroll
        for (int kk = 0; kk < 2; ++kk)
#pragma unroll
            for (int mi = 0; mi < 4; ++mi)
#pragma unroll
                for (int ni = 0; ni < 4; ++ni)
                    acc[mi][ni] = MFMA16(af[mi][kk], bf[ni][kk], acc[mi][ni]);
        __builtin_amdgcn_s_setprio(0);

        RBAR();                                    // all waves done reading cur
        cur ^= 1;
    }

#pragma unroll
    for (int ni = 0; ni < 4; ++ni) {
        const int n = n0 + wn * 64 + ni * 16 + li;
        const float bv = bias[n];
        const int s = n >> 10, h = (n >> 6) & 15, d = n & 63;
#pragma unroll
        for (int mi = 0; mi < 4; ++mi) {
            const int mB = m0 + wm * 64 + mi * 16 + g * 4;
            float v0 = acc[mi][ni][0] + bv, v1 = acc[mi][ni][1] + bv;
            float v2 = acc[mi][ni][2] + bv, v3 = acc[mi][ni][3] + bv;
            if (MODE == 0) {
                const int b = mB >> 11, tt = mB & 2047;
                if (s == 2) {
                    unsigned pk01, pk23;
                    asm("v_cvt_pk_bf16_f32 %0, %1, %2" : "=v"(pk01) : "v"(v0), "v"(v1));
                    asm("v_cvt_pk_bf16_f32 %0, %1, %2" : "=v"(pk23) : "v"(v2), "v"(v3));
                    unsigned short* dst = vtp + ((size_t)(b * 16 + h) * 64 + d) * 2048 + tt;
                    *(unsigned*)dst = pk01;
                    *(unsigned*)(dst + 2) = pk23;
                } else {
                    const float sc2 = (s == 0) ? 0.1803368801111143f : 1.0f;  // 0.125*log2e
                    unsigned short* dst =
                        ((s == 0) ? qp : kp) + ((size_t)(b * 16 + h) * 2048 + tt) * 64 + d;
                    dst[0]   = f2bf(v0 * sc2);
                    dst[64]  = f2bf(v1 * sc2);
                    dst[128] = f2bf(v2 * sc2);
                    dst[192] = f2bf(v3 * sc2);
                }
            } else {
                float* dst = outp + (size_t)mB * N + n;
                dst[0] = v0; dst[N] = v1; dst[2 * N] = v2; dst[3 * N] = v3;
            }
        }
    }
}

// ---------------------------------------------------------------------------
// Flash attention, causal.
//   - 4 waves/block; block owns q-tile pair (A = 31-bx heavy, B = bx light);
//     single kv-loop; gl_lds16 staging (round-8 proven), shared by all.
//   - T4 counted-vmcnt pipeline, raw barriers, vmcnt never 0 mid-loop:
//       K dbuf (2x8KB): STAGE_K(t+1) at top, vmcnt(4) -> K(t) ready;
//       V single (8KB): STAGE_V(t+1) after PV barrier, vmcnt(2) -> V(t) ready
//       (V load hides under next iter's QK+softmax).
//     LDS = 16K + 8K + 9K Ps = 33.8KB -> 4 blocks/CU, grid co-resident.
//   - XCD swizzle; swapped QK^T; defer-max; setprio; exp2 domain.
// ---------------------------------------------------------------------------
__device__ __forceinline__ void qk_softmax(
    const unsigned short* Ks, const s16x8 qf0, const s16x8 qf1,
    f32x4 (&O)[4], float& m, float& l,
    unsigned short (*Psw)[72], s16x8& pf0, s16x8& pf1,
    int kbase, int wq0, int qrow, int g, int li)
{
    f32x4 sT[4];
    __builtin_amdgcn_s_setprio(1);
#pragma unroll
    for (int nf = 0; nf < 4; ++nf) {
        const int r = nf * 16 + li;
        s16x8 kf0 = *(const s16x8*)(Ks + r * 64 + ((g ^ (li & 7)) << 3));
        s16x8 kf1 = *(const s16x8*)(Ks + r * 64 + (((g + 4) ^ (li & 7)) << 3));
        f32x4 a = {};
        a = MFMA16(kf0, qf0, a);
        a = MFMA16(kf1, qf1, a);
        sT[nf] = a;
    }
    __builtin_amdgcn_s_setprio(0);

    if (kbase + 63 > wq0) {
#pragma unroll
        for (int nf = 0; nf < 4; ++nf)
#pragma unroll
            for (int r = 0; r < 4; ++r)
                if (kbase + nf * 16 + g * 4 + r > qrow) sT[nf][r] = -1e30f;
    }

    float t0 = fmaxf(fmaxf(sT[0][0], sT[0][1]), sT[0][2]);
    float t1 = fmaxf(fmaxf(sT[0][3], sT[1][0]), sT[1][1]);
    float t2 = fmaxf(fmaxf(sT[1][2], sT[1][3]), sT[2][0]);
    float t3 = fmaxf(fmaxf(sT[2][1], sT[2][2]), sT[2][3]);
    float t4 = fmaxf(fmaxf(sT[3][0], sT[3][1]), sT[3][2]);
    float mx = fmaxf(fmaxf(t0, t1), t2);
    mx = fmaxf(fmaxf(mx, t3), fmaxf(t4, sT[3][3]));
    mx = fmaxf(mx, __shfl_xor(mx, 16));
    mx = fmaxf(mx, __shfl_xor(mx, 32));

    if (__any(mx > m + 8.f)) {
        const float mnew = fmaxf(m, mx);
        const float fac  = __builtin_amdgcn_exp2f(m - mnew);
        m = mnew;
        l *= fac;
        float facr[4];
#pragma unroll
        for (int r = 0; r < 4; ++r) facr[r] = __shfl(fac, g * 4 + r);
#pragma unroll
        for (int nf = 0; nf < 4; ++nf)
#pragma unroll
            for (int r = 0; r < 4; ++r) O[nf][r] *= facr[r];
    }

    float rs = 0.f;
#pragma unroll
    for (int nf = 0; nf < 4; ++nf)
#pragma unroll
        for (int r = 0; r < 4; ++r) {
            float p = __builtin_amdgcn_exp2f(sT[nf][r] - m);
            sT[nf][r] = p;
            rs += p;
        }
    rs += __shfl_xor(rs, 16);
    rs += __shfl_xor(rs, 32);
    l += rs;

#pragma unroll
    for (int nf = 0; nf < 4; ++nf) {
        unsigned pk0, pk1;
        asm("v_cvt_pk_bf16_f32 %0, %1, %2" : "=v"(pk0) : "v"(sT[nf][0]), "v"(sT[nf][1]));
        asm("v_cvt_pk_bf16_f32 %0, %1, %2" : "=v"(pk1) : "v"(sT[nf][2]), "v"(sT[nf][3]));
        uint2 pv; pv.x = pk0; pv.y = pk1;
        *(uint2*)(&Psw[li][nf * 16 + g * 4]) = pv;
    }
    pf0 = *(const s16x8*)(&Psw[li][g * 8]);
    pf1 = *(const s16x8*)(&Psw[li][32 + g * 8]);
}

__global__ __launch_bounds__(256, 4) void attn_k(
    const unsigned short* __restrict__ qbuf,
    const unsigned short* __restrict__ kbuf,
    const unsigned short* __restrict__ vtbuf,
    unsigned short* __restrict__ ybuf)
{
    __shared__ unsigned short Ks[2][4096];    // [64 keys][64 d], swizzled, dbuf
    __shared__ unsigned short Vs[4096];       // [64 d][64 keys], swizzled
    __shared__ unsigned short Ps[4][16][72];  // per-wave P staging (shared A/B)

    const int tid  = threadIdx.x;
    const int lane = tid & 63, w = tid >> 6;
    const int g = lane >> 4, li = lane & 15;

    // XCD-aware remap: XCD x (= id%8) owns bh in [8x, 8x+8) -> K/V fits L2
    const int id   = blockIdx.x;
    const int slot = id >> 3;
    const int bh   = (id & 7) * 8 + (slot & 7);
    const int bx   = slot >> 3;               // 0..15
    const int qtA  = 31 - bx, qtB = bx;

    const unsigned short* qb  = qbuf  + (size_t)bh * 131072;
    const unsigned short* kb  = kbuf  + (size_t)bh * 131072;
    const unsigned short* vtb = vtbuf + (size_t)bh * 131072;
    const int b = bh >> 4, h = bh & 15;

    const int srow = lane >> 3;
    const int ssw  = ((lane & 7) ^ srow) * 8;     // pre-swizzled source chunk

    auto STAGE_K = [&](int buf, int kbase) {      // 2 loads/thread
#pragma unroll
        for (int jj = 0; jj < 2; ++jj) {
            const int j = w * 2 + jj, row = j * 8 + srow;
            gl_lds16(kb + (size_t)(kbase + row) * 64 + ssw, &Ks[buf][j * 512]);
        }
    };
    auto STAGE_V = [&](int kbase) {               // 2 loads/thread
#pragma unroll
        for (int jj = 0; jj < 2; ++jj) {
            const int j = w * 2 + jj, row = j * 8 + srow;
            gl_lds16(vtb + (size_t)row * 2048 + kbase + ssw, &Vs[j * 512]);
        }
    };

    const int wqA = qtA * 64 + w * 16, qrowA = wqA + li;
    const int wqB = qtB * 64 + w * 16, qrowB = wqB + li;

    const unsigned short* qrA = qb + (size_t)qrowA * 64 + g * 8;
    const s16x8 qfA0 = *(const s16x8*)qrA;
    const s16x8 qfA1 = *(const s16x8*)(qrA + 32);
    const unsigned short* qrB = qb + (size_t)qrowB * 64 + g * 8;
    const s16x8 qfB0 = *(const s16x8*)qrB;
    const s16x8 qfB1 = *(const s16x8*)(qrB + 32);

    f32x4 OA[4] = {}, OB[4] = {};
    float mA = -1e30f, lA = 0.f, mB = -1e30f, lB = 0.f;

    const int nkb = qtA + 1;
    STAGE_K(0, 0);
    STAGE_V(0);
    VMCNT(0);
    RBAR();

    int bK = 0;
    for (int t = 0; t < nkb; ++t) {
        const int kbase = t * 64;
        const bool actB = (t <= qtB);
        const bool more = (t + 1 < nkb);

        // ---- phase 1: K(t) ready (counted), issue K(t+1)
        if (more) {
            STAGE_K(bK ^ 1, kbase + 64);
            VMCNT(4);          // outstanding: V(t)2 + K(t+1)2 remain
        } else {
            VMCNT(2);          // outstanding: V(t)2 remain
        }
        RBAR();

        // ---- phase 2: QK^T + softmax (K stage of t+1 in flight)
        s16x8 pfA0, pfA1, pfB0, pfB1;
        qk_softmax(&Ks[bK][0], qfA0, qfA1, OA, mA, lA, &Ps[w][0], pfA0, pfA1,
                   kbase, wqA, qrowA, g, li);
        if (actB)
            qk_softmax(&Ks[bK][0], qfB0, qfB1, OB, mB, lB, &Ps[w][0], pfB0, pfB1,
                       kbase, wqB, qrowB, g, li);

        // ---- phase 3: V(t) ready (counted)
        if (more) VMCNT(2); else VMCNT(0);
        RBAR();

        // ---- phase 4: PV
        __builtin_amdgcn_s_setprio(1);
#pragma unroll
        for (int nf = 0; nf < 4; ++nf) {
            const int d = nf * 16 + li;
            s16x8 vf0 = *(const s16x8*)(Vs + d * 64 + ((g ^ (li & 7)) << 3));
            s16x8 vf1 = *(const s16x8*)(Vs + d * 64 + (((g + 4) ^ (li & 7)) << 3));
            OA[nf] = MFMA16(pfA0, vf0, OA[nf]);
            OA[nf] = MFMA16(pfA1, vf1, OA[nf]);
            if (actB) {
                OB[nf] = MFMA16(pfB0, vf0, OB[nf]);
                OB[nf] = MFMA16(pfB1, vf1, OB[nf]);
            }
        }
        __builtin_amdgcn_s_setprio(0);

        if (more) {
            RBAR();                       // all waves done reading Vs (and Ks[bK])
            STAGE_V(kbase + 64);          // V(t+1) hides under next QK+softmax
        }
        bK ^= 1;
    }

    // epilogue: per-tile linv broadcast to D-layout rows, write y
    {
        const float linv = __builtin_amdgcn_rcpf(lA);
        float lr[4];
#pragma unroll
        for (int r = 0; r < 4; ++r) lr[r] = __shfl(linv, g * 4 + r);
#pragma unroll
        for (int nf = 0; nf < 4; ++nf)
#pragma unroll
            for (int r = 0; r < 4; ++r) {
                const int row = wqA + g * 4 + r;
                ybuf[((size_t)(b * 2048 + row)) * 1024 + h * 64 + nf * 16 + li] =
                    f2bf(OA[nf][r] * lr[r]);
            }
    }
    {
        const float linv = __builtin_amdgcn_rcpf(lB);
        float lr[4];
#pragma unroll
        for (int r = 0; r < 4; ++r) lr[r] = __shfl(linv, g * 4 + r);
#pragma unroll
        for (int nf = 0; nf < 4; ++nf)
#pragma unroll
            for (int r = 0; r < 4; ++r) {
                const int row = wqB + g * 4 + r;
                ybuf[((size_t)(b * 2048 + row)) * 1024 + h * 64 + nf * 16 + li] =
                    f2bf(OB[nf][r] * lr[r]);
            }
    }
}

extern "C" void kernel_launch(void* const* d_in, const int* in_sizes, int n_in,
                              void* d_out, int out_size, void* d_ws, size_t ws_size,
                              hipStream_t stream)
{
    const float* x    = (const float*)d_in[0];
    const float* Wqkv = (const float*)d_in[1];
    const float* bqkv = (const float*)d_in[2];
    const float* Wout = (const float*)d_in[3];
    const float* bout = (const float*)d_in[4];

    unsigned short* ws0 = (unsigned short*)d_ws;               // q -> WoutT
    unsigned short* ws1 = ws0 + (size_t)8388608;               // k
    unsigned short* ws2 = ws0 + (size_t)2 * 8388608;           // vT
    unsigned short* ws3 = ws0 + (size_t)3 * 8388608;           // y

    unsigned short* xbf   = (unsigned short*)d_out;
    unsigned short* WqkvT = xbf + (size_t)8388608;

    cvt_x<<<8192, 256, 0, stream>>>(x, xbf, 2097152);
    cvt_tr<<<dim3(16, 48), 256, 0, stream>>>(Wqkv, WqkvT, 1024, 3072);
    gemm_bt<0><<<dim3(64, 24), 256, 0, stream>>>(
        xbf, WqkvT, bqkv, ws0, ws1, ws2, nullptr, 8192, 3072, 1024);
    attn_k<<<1024, 256, 0, stream>>>(ws0, ws1, ws2, ws3);
    cvt_tr<<<dim3(16, 16), 256, 0, stream>>>(Wout, ws0, 1024, 1024);
    gemm_bt<1><<<dim3(64, 8), 256, 0, stream>>>(
        ws3, ws0, bout, nullptr, nullptr, nullptr, (float*)d_out, 8192, 1024, 1024);
}